// Round 1
// baseline (836.717 us; speedup 1.0000x reference)
//
#include <hip/hip_runtime.h>

typedef unsigned short u16;
typedef __bf16 bf16x8 __attribute__((ext_vector_type(8)));
typedef float f32x4 __attribute__((ext_vector_type(4)));

// ---------- helpers ----------
__device__ __forceinline__ u16 f2bf(float f) {
  unsigned u = __builtin_bit_cast(unsigned, f);
  unsigned lsb = (u >> 16) & 1u;
  u += 0x7fffu + lsb;                 // round-to-nearest-even
  return (u16)(u >> 16);
}

__device__ __forceinline__ void gld_lds16(const u16* g, u16* l) {
  __builtin_amdgcn_global_load_lds(
      (__attribute__((address_space(1))) void*)g,
      (__attribute__((address_space(3))) void*)l, 16, 0, 0);
}

// ---------- LayerNorm (torch-style: unbiased var, alpha*(x-mean)/(std+eps)+bias) ----------
__global__ __launch_bounds__(256) void ln_kernel(
    const float* __restrict__ x, u16* __restrict__ out,
    const float* __restrict__ alpha_p, const float* __restrict__ beta_p) {
  const int row = blockIdx.x;
  const int t = threadIdx.x;
  const float4 v = reinterpret_cast<const float4*>(x + (size_t)row * 1024)[t];
  float s = v.x + v.y + v.z + v.w;
  float sq = v.x * v.x + v.y * v.y + v.z * v.z + v.w * v.w;
#pragma unroll
  for (int off = 32; off > 0; off >>= 1) {
    s += __shfl_down(s, off);
    sq += __shfl_down(sq, off);
  }
  __shared__ float red[8];
  const int w = t >> 6;
  if ((t & 63) == 0) { red[w] = s; red[4 + w] = sq; }
  __syncthreads();
  const float ts = red[0] + red[1] + red[2] + red[3];
  const float tq = red[4] + red[5] + red[6] + red[7];
  const float mean = ts * (1.0f / 1024.0f);
  float var = (tq - ts * mean) * (1.0f / 1023.0f);
  var = fmaxf(var, 0.0f);
  const float rden = 1.0f / (sqrtf(var) + 1e-5f);
  const float a = alpha_p[0], bb = beta_p[0];
  ushort4 ov;
  ov.x = f2bf(a * (v.x - mean) * rden + bb);
  ov.y = f2bf(a * (v.y - mean) * rden + bb);
  ov.z = f2bf(a * (v.z - mean) * rden + bb);
  ov.w = f2bf(a * (v.w - mean) * rden + bb);
  reinterpret_cast<ushort4*>(out + (size_t)row * 1024)[t] = ov;
}

// ---------- weight convert fp32 [K][N] -> bf16 transposed [N][K] ----------
__global__ __launch_bounds__(256) void wcvt_t(
    const float* __restrict__ w, u16* __restrict__ wt, int K, int N) {
  __shared__ float tile[32][33];
  const int n0 = blockIdx.x * 32, k0 = blockIdx.y * 32;
  const int tx = threadIdx.x, ty = threadIdx.y;
#pragma unroll
  for (int i = 0; i < 4; ++i)
    tile[ty + i * 8][tx] = w[(size_t)(k0 + ty + i * 8) * N + n0 + tx];
  __syncthreads();
#pragma unroll
  for (int i = 0; i < 4; ++i)
    wt[(size_t)(n0 + ty + i * 8) * K + k0 + tx] = f2bf(tile[tx][ty + i * 8]);
}

// ---------- bf16 transpose per batch: v [B][S=2048][D=1024] -> vt [B][D=1024][S=2048] ----------
__global__ __launch_bounds__(256) void vtrans(
    const u16* __restrict__ v, u16* __restrict__ vt) {
  __shared__ u16 tile[32][33];
  const int d0 = blockIdx.x * 32, s0 = blockIdx.y * 32, b = blockIdx.z;
  const int tx = threadIdx.x, ty = threadIdx.y;
  const u16* vb = v + (size_t)b * 2048 * 1024;
  u16* vo = vt + (size_t)b * 1024 * 2048;
#pragma unroll
  for (int i = 0; i < 4; ++i)
    tile[ty + i * 8][tx] = vb[(size_t)(s0 + ty + i * 8) * 1024 + d0 + tx];
  __syncthreads();
#pragma unroll
  for (int i = 0; i < 4; ++i)
    vo[(size_t)(d0 + ty + i * 8) * 2048 + s0 + tx] = tile[tx][ty + i * 8];
}

// ---------- GEMM: C[M,N] = A[M,K](bf16) * Bt[N,K]^T(bf16) + bias, m97 structure ----------
// EPI 0: bf16 out.  EPI 1: f32 out = acc+bias+res.  EPI 2: bf16 relu out.
template <int EPI>
__global__ __launch_bounds__(256) void gemm_bt(
    const u16* __restrict__ A, const u16* __restrict__ Bt,
    const float* __restrict__ bias, const float* __restrict__ res,
    void* __restrict__ Cout, int M, int N, int K) {
  __shared__ u16 As[128 * 32];
  __shared__ u16 Bs[128 * 32];
  const int tid = threadIdx.x;
  const int l = tid & 63;
  const int w = tid >> 6;
  const int wr = w >> 1, wc = w & 1;
  const int m0 = blockIdx.y * 128, n0 = blockIdx.x * 128;
  const int lr = l & 15, lk = (l >> 4) * 8;

  f32x4 acc[4][4];
#pragma unroll
  for (int i = 0; i < 4; ++i)
#pragma unroll
    for (int j = 0; j < 4; ++j) acc[i][j] = f32x4{0.f, 0.f, 0.f, 0.f};

  const int srow = tid >> 2;
  const int scol = (tid & 3) * 8;
  const u16* gA0 = A + (size_t)(m0 + srow) * K + scol;
  const u16* gA1 = A + (size_t)(m0 + 64 + srow) * K + scol;
  const u16* gB0 = Bt + (size_t)(n0 + srow) * K + scol;
  const u16* gB1 = Bt + (size_t)(n0 + 64 + srow) * K + scol;
  u16* lA0 = &As[tid * 8];
  u16* lA1 = &As[2048 + tid * 8];
  u16* lB0 = &Bs[tid * 8];
  u16* lB1 = &Bs[2048 + tid * 8];

  for (int k0 = 0; k0 < K; k0 += 32) {
    gld_lds16(gA0 + k0, lA0);
    gld_lds16(gA1 + k0, lA1);
    gld_lds16(gB0 + k0, lB0);
    gld_lds16(gB1 + k0, lB1);
    __syncthreads();
    bf16x8 a[4], b[4];
#pragma unroll
    for (int mf = 0; mf < 4; ++mf)
      a[mf] = *reinterpret_cast<const bf16x8*>(&As[(wr * 64 + mf * 16 + lr) * 32 + lk]);
#pragma unroll
    for (int nf = 0; nf < 4; ++nf)
      b[nf] = *reinterpret_cast<const bf16x8*>(&Bs[(wc * 64 + nf * 16 + lr) * 32 + lk]);
#pragma unroll
    for (int mf = 0; mf < 4; ++mf)
#pragma unroll
      for (int nf = 0; nf < 4; ++nf)
        acc[mf][nf] = __builtin_amdgcn_mfma_f32_16x16x32_bf16(a[mf], b[nf], acc[mf][nf], 0, 0, 0);
    __syncthreads();
  }

#pragma unroll
  for (int mf = 0; mf < 4; ++mf) {
#pragma unroll
    for (int nf = 0; nf < 4; ++nf) {
      const int col = n0 + wc * 64 + nf * 16 + lr;
      const float bv = bias[col];
#pragma unroll
      for (int j = 0; j < 4; ++j) {
        const int row = m0 + wr * 64 + mf * 16 + (l >> 4) * 4 + j;
        const size_t idx = (size_t)row * N + col;
        const float vv = acc[mf][nf][j] + bv;
        if (EPI == 0)
          ((u16*)Cout)[idx] = f2bf(vv);
        else if (EPI == 1)
          ((float*)Cout)[idx] = vv + res[idx];
        else
          ((u16*)Cout)[idx] = f2bf(fmaxf(vv, 0.f));
      }
    }
  }
}

// ---------- flash attention fwd: q,k [B*S,1024] (head=col h*64), vt [B][1024][2048] ----------
__global__ __launch_bounds__(256) void attn_fwd(
    const u16* __restrict__ q, const u16* __restrict__ k,
    const u16* __restrict__ vt, const int* __restrict__ mask,
    u16* __restrict__ ctx) {
  __shared__ u16 plds[4][16][80];  // per-wave P tile, padded (160B row stride)
  const int tid = threadIdx.x;
  const int l = tid & 63;
  const int w = tid >> 6;
  const int bh = blockIdx.y;
  const int b = bh >> 4, h = bh & 15;
  const int r0 = (blockIdx.x * 4 + w) * 16;
  const int lr = l & 15, lg = l >> 4, lk = lg * 8;

  const u16* qb = q + (size_t)b * 2048 * 1024 + h * 64;
  const u16* kp = k + (size_t)b * 2048 * 1024 + h * 64;
  const u16* vb = vt + ((size_t)b * 1024 + h * 64) * 2048;
  const int* mb = mask + (size_t)b * 2048;

  bf16x8 aq[2];
#pragma unroll
  for (int ks = 0; ks < 2; ++ks)
    aq[ks] = *reinterpret_cast<const bf16x8*>(qb + (size_t)(r0 + lr) * 1024 + ks * 32 + lk);

  float mrun[4], lrun[4];
  f32x4 o[4];
#pragma unroll
  for (int j = 0; j < 4; ++j) { mrun[j] = -1e30f; lrun[j] = 0.f; }
#pragma unroll
  for (int d = 0; d < 4; ++d) o[d] = f32x4{0.f, 0.f, 0.f, 0.f};

  for (int kb0 = 0; kb0 < 2048; kb0 += 64) {
    f32x4 s[4];
#pragma unroll
    for (int cf = 0; cf < 4; ++cf) {
      f32x4 acc = f32x4{0.f, 0.f, 0.f, 0.f};
#pragma unroll
      for (int ks = 0; ks < 2; ++ks) {
        bf16x8 bk = *reinterpret_cast<const bf16x8*>(
            kp + (size_t)(kb0 + cf * 16 + lr) * 1024 + ks * 32 + lk);
        acc = __builtin_amdgcn_mfma_f32_16x16x32_bf16(aq[ks], bk, acc, 0, 0, 0);
      }
      const bool live = (mb[kb0 + cf * 16 + lr] != 0);
#pragma unroll
      for (int j = 0; j < 4; ++j) s[cf][j] = live ? acc[j] * 0.125f : -1e9f;
    }
#pragma unroll
    for (int j = 0; j < 4; ++j) {
      float pm = fmaxf(fmaxf(s[0][j], s[1][j]), fmaxf(s[2][j], s[3][j]));
#pragma unroll
      for (int off = 8; off > 0; off >>= 1) pm = fmaxf(pm, __shfl_xor(pm, off));
      const float mn = fmaxf(mrun[j], pm);
      const float corr = __expf(mrun[j] - mn);
      mrun[j] = mn;
      float rs = 0.f;
#pragma unroll
      for (int cf = 0; cf < 4; ++cf) {
        const float p = __expf(s[cf][j] - mn);
        s[cf][j] = p;
        rs += p;
      }
#pragma unroll
      for (int off = 8; off > 0; off >>= 1) rs += __shfl_xor(rs, off);
      lrun[j] = lrun[j] * corr + rs;
#pragma unroll
      for (int d = 0; d < 4; ++d) o[d][j] *= corr;
    }
    // P -> LDS (bf16), then re-read in A-fragment layout (wave-private, no barrier)
#pragma unroll
    for (int cf = 0; cf < 4; ++cf)
#pragma unroll
      for (int j = 0; j < 4; ++j)
        plds[w][lg * 4 + j][cf * 16 + lr] = f2bf(s[cf][j]);
    asm volatile("s_waitcnt lgkmcnt(0)" ::: "memory");
    bf16x8 pa[2];
#pragma unroll
    for (int ks = 0; ks < 2; ++ks)
      pa[ks] = *reinterpret_cast<const bf16x8*>(&plds[w][lr][ks * 32 + lk]);
#pragma unroll
    for (int d = 0; d < 4; ++d) {
#pragma unroll
      for (int ks = 0; ks < 2; ++ks) {
        bf16x8 bv = *reinterpret_cast<const bf16x8*>(
            vb + (size_t)(d * 16 + lr) * 2048 + kb0 + ks * 32 + lk);
        o[d] = __builtin_amdgcn_mfma_f32_16x16x32_bf16(pa[ks], bv, o[d], 0, 0, 0);
      }
    }
  }
#pragma unroll
  for (int d = 0; d < 4; ++d) {
#pragma unroll
    for (int j = 0; j < 4; ++j) {
      const int row = r0 + lg * 4 + j;
      const float val = o[d][j] / lrun[j];
      ctx[((size_t)b * 2048 + row) * 1024 + h * 64 + d * 16 + lr] = f2bf(val);
    }
  }
}

// ---------- launch ----------
extern "C" void kernel_launch(void* const* d_in, const int* in_sizes, int n_in,
                              void* d_out, int out_size, void* d_ws, size_t ws_size,
                              hipStream_t stream) {
  const float* x = (const float*)d_in[0];
  const int* mask = (const int*)d_in[1];
  const float* wq = (const float*)d_in[2];
  const float* bq = (const float*)d_in[3];
  const float* wk = (const float*)d_in[4];
  const float* bk = (const float*)d_in[5];
  const float* wv = (const float*)d_in[6];
  const float* bv = (const float*)d_in[7];
  const float* wo = (const float*)d_in[8];
  const float* bo = (const float*)d_in[9];
  const float* w1 = (const float*)d_in[10];
  const float* b1 = (const float*)d_in[11];
  const float* w2 = (const float*)d_in[12];
  const float* b2 = (const float*)d_in[13];
  const float* ln1a = (const float*)d_in[14];
  const float* ln1b = (const float*)d_in[15];
  const float* ln2a = (const float*)d_in[16];
  const float* ln2b = (const float*)d_in[17];

  char* ws = (char*)d_ws;
  const size_t MB = 1024ull * 1024ull;
  // requires ws_size >= 152 MB (regions reused across phases)
  u16* WTQ = (u16*)(ws + 0 * MB);
  u16* WTK = (u16*)(ws + 2 * MB);
  u16* WTV = (u16*)(ws + 4 * MB);
  u16* WTO = (u16*)(ws + 6 * MB);
  u16* W1T = (u16*)(ws + 8 * MB);   // [4096][1024]
  u16* W2T = (u16*)(ws + 16 * MB);  // [1024][4096]
  u16* XN = (u16*)(ws + 24 * MB);   // xn1; reused as CTX
  u16* Qb = (u16*)(ws + 40 * MB);
  u16* Kb = (u16*)(ws + 56 * MB);
  u16* Vb = (u16*)(ws + 72 * MB);   // reused as XN2
  u16* VT = (u16*)(ws + 88 * MB);   // reused as H1 (88..152MB)
  float* X2 = (float*)(ws + 40 * MB);  // overwrites Qb/Kb after attention
  u16* CTX = XN;
  u16* XN2 = Vb;
  u16* H1 = VT;

  dim3 bt(32, 8);
  // weights: bf16 + transpose
  wcvt_t<<<dim3(32, 32), bt, 0, stream>>>(wq, WTQ, 1024, 1024);
  wcvt_t<<<dim3(32, 32), bt, 0, stream>>>(wk, WTK, 1024, 1024);
  wcvt_t<<<dim3(32, 32), bt, 0, stream>>>(wv, WTV, 1024, 1024);
  wcvt_t<<<dim3(32, 32), bt, 0, stream>>>(wo, WTO, 1024, 1024);
  wcvt_t<<<dim3(128, 32), bt, 0, stream>>>(w1, W1T, 1024, 4096);
  wcvt_t<<<dim3(32, 128), bt, 0, stream>>>(w2, W2T, 4096, 1024);

  // LN1
  ln_kernel<<<8192, 256, 0, stream>>>(x, XN, ln1a, ln1b);
  // QKV
  gemm_bt<0><<<dim3(8, 64), 256, 0, stream>>>(XN, WTQ, bq, nullptr, Qb, 8192, 1024, 1024);
  gemm_bt<0><<<dim3(8, 64), 256, 0, stream>>>(XN, WTK, bk, nullptr, Kb, 8192, 1024, 1024);
  gemm_bt<0><<<dim3(8, 64), 256, 0, stream>>>(XN, WTV, bv, nullptr, Vb, 8192, 1024, 1024);
  // V transpose for PV fragments
  vtrans<<<dim3(32, 64, 4), bt, 0, stream>>>(Vb, VT);
  // attention
  attn_fwd<<<dim3(32, 64), 256, 0, stream>>>(Qb, Kb, VT, mask, CTX);
  // O-proj + residual (fp32)
  gemm_bt<1><<<dim3(8, 64), 256, 0, stream>>>(CTX, WTO, bo, x, X2, 8192, 1024, 1024);
  // LN2
  ln_kernel<<<8192, 256, 0, stream>>>(X2, XN2, ln2a, ln2b);
  // FFN
  gemm_bt<2><<<dim3(32, 64), 256, 0, stream>>>(XN2, W1T, b1, nullptr, H1, 8192, 4096, 1024);
  gemm_bt<1><<<dim3(8, 64), 256, 0, stream>>>(H1, W2T, b2, X2, (float*)d_out, 8192, 1024, 4096);
}

// Round 2
// 615.246 us; speedup vs baseline: 1.3600x; 1.3600x over previous
//
#include <hip/hip_runtime.h>

typedef unsigned short u16;
typedef __bf16 bf16x8 __attribute__((ext_vector_type(8)));
typedef float f32x4 __attribute__((ext_vector_type(4)));

// ---------- helpers ----------
__device__ __forceinline__ u16 f2bf(float f) {
  unsigned u = __builtin_bit_cast(unsigned, f);
  unsigned lsb = (u >> 16) & 1u;
  u += 0x7fffu + lsb;                 // round-to-nearest-even
  return (u16)(u >> 16);
}

__device__ __forceinline__ void gld_lds16(const u16* g, u16* l) {
  __builtin_amdgcn_global_load_lds(
      (__attribute__((address_space(1))) void*)g,
      (__attribute__((address_space(3))) void*)l, 16, 0, 0);
}

// ---------- LayerNorm (torch-style: unbiased var, alpha*(x-mean)/(std+eps)+bias) ----------
__global__ __launch_bounds__(256) void ln_kernel(
    const float* __restrict__ x, u16* __restrict__ out,
    const float* __restrict__ alpha_p, const float* __restrict__ beta_p) {
  const int row = blockIdx.x;
  const int t = threadIdx.x;
  const float4 v = reinterpret_cast<const float4*>(x + (size_t)row * 1024)[t];
  float s = v.x + v.y + v.z + v.w;
  float sq = v.x * v.x + v.y * v.y + v.z * v.z + v.w * v.w;
#pragma unroll
  for (int off = 32; off > 0; off >>= 1) {
    s += __shfl_down(s, off);
    sq += __shfl_down(sq, off);
  }
  __shared__ float red[8];
  const int w = t >> 6;
  if ((t & 63) == 0) { red[w] = s; red[4 + w] = sq; }
  __syncthreads();
  const float ts = red[0] + red[1] + red[2] + red[3];
  const float tq = red[4] + red[5] + red[6] + red[7];
  const float mean = ts * (1.0f / 1024.0f);
  float var = (tq - ts * mean) * (1.0f / 1023.0f);
  var = fmaxf(var, 0.0f);
  const float rden = 1.0f / (sqrtf(var) + 1e-5f);
  const float a = alpha_p[0], bb = beta_p[0];
  ushort4 ov;
  ov.x = f2bf(a * (v.x - mean) * rden + bb);
  ov.y = f2bf(a * (v.y - mean) * rden + bb);
  ov.z = f2bf(a * (v.z - mean) * rden + bb);
  ov.w = f2bf(a * (v.w - mean) * rden + bb);
  reinterpret_cast<ushort4*>(out + (size_t)row * 1024)[t] = ov;
}

// ---------- weight convert fp32 [K][N] -> bf16 transposed [N][K] ----------
__global__ __launch_bounds__(256) void wcvt_t(
    const float* __restrict__ w, u16* __restrict__ wt, int K, int N) {
  __shared__ float tile[32][33];
  const int n0 = blockIdx.x * 32, k0 = blockIdx.y * 32;
  const int tx = threadIdx.x, ty = threadIdx.y;
#pragma unroll
  for (int i = 0; i < 4; ++i)
    tile[ty + i * 8][tx] = w[(size_t)(k0 + ty + i * 8) * N + n0 + tx];
  __syncthreads();
#pragma unroll
  for (int i = 0; i < 4; ++i)
    wt[(size_t)(n0 + ty + i * 8) * K + k0 + tx] = f2bf(tile[tx][ty + i * 8]);
}

// ---------- bias concat [1024]x3 -> [3072] ----------
__global__ __launch_bounds__(256) void pack_bias(
    const float* __restrict__ a, const float* __restrict__ b,
    const float* __restrict__ c, float* __restrict__ o) {
  const int i = blockIdx.x * 256 + threadIdx.x;
  o[i] = (i < 1024) ? a[i] : ((i < 2048) ? b[i - 1024] : c[i - 2048]);
}

// ---------- bf16 transpose per batch: v [B][S][vstride] -> vt [B][1024][2048] ----------
__global__ __launch_bounds__(256) void vtrans(
    const u16* __restrict__ v, u16* __restrict__ vt, int vstride) {
  __shared__ u16 tile[32][33];
  const int d0 = blockIdx.x * 32, s0 = blockIdx.y * 32, b = blockIdx.z;
  const int tx = threadIdx.x, ty = threadIdx.y;
  const u16* vb = v + (size_t)b * 2048 * vstride;
  u16* vo = vt + (size_t)b * 1024 * 2048;
#pragma unroll
  for (int i = 0; i < 4; ++i)
    tile[ty + i * 8][tx] = vb[(size_t)(s0 + ty + i * 8) * vstride + d0 + tx];
  __syncthreads();
#pragma unroll
  for (int i = 0; i < 4; ++i)
    vo[(size_t)(d0 + ty + i * 8) * 2048 + s0 + tx] = tile[tx][ty + i * 8];
}

// ---------- GEMM: C[M,N] = A[M,K](bf16) * Bt[N,K]^T(bf16) + bias, m97 structure ----------
// EPI 0: bf16 out.  EPI 1: f32 out = acc+bias+res.  EPI 2: bf16 relu out.
template <int EPI>
__global__ __launch_bounds__(256) void gemm_bt(
    const u16* __restrict__ A, const u16* __restrict__ Bt,
    const float* __restrict__ bias, const float* __restrict__ res,
    void* __restrict__ Cout, int M, int N, int K) {
  __shared__ u16 As[128 * 32];
  __shared__ u16 Bs[128 * 32];
  const int tid = threadIdx.x;
  const int l = tid & 63;
  const int w = tid >> 6;
  const int wr = w >> 1, wc = w & 1;
  const int m0 = blockIdx.y * 128, n0 = blockIdx.x * 128;
  const int lr = l & 15, lk = (l >> 4) * 8;

  f32x4 acc[4][4];
#pragma unroll
  for (int i = 0; i < 4; ++i)
#pragma unroll
    for (int j = 0; j < 4; ++j) acc[i][j] = f32x4{0.f, 0.f, 0.f, 0.f};

  const int srow = tid >> 2;
  const int scol = (tid & 3) * 8;
  const u16* gA0 = A + (size_t)(m0 + srow) * K + scol;
  const u16* gA1 = A + (size_t)(m0 + 64 + srow) * K + scol;
  const u16* gB0 = Bt + (size_t)(n0 + srow) * K + scol;
  const u16* gB1 = Bt + (size_t)(n0 + 64 + srow) * K + scol;
  u16* lA0 = &As[tid * 8];
  u16* lA1 = &As[2048 + tid * 8];
  u16* lB0 = &Bs[tid * 8];
  u16* lB1 = &Bs[2048 + tid * 8];

  for (int k0 = 0; k0 < K; k0 += 32) {
    gld_lds16(gA0 + k0, lA0);
    gld_lds16(gA1 + k0, lA1);
    gld_lds16(gB0 + k0, lB0);
    gld_lds16(gB1 + k0, lB1);
    __syncthreads();
    bf16x8 a[4], b[4];
#pragma unroll
    for (int mf = 0; mf < 4; ++mf)
      a[mf] = *reinterpret_cast<const bf16x8*>(&As[(wr * 64 + mf * 16 + lr) * 32 + lk]);
#pragma unroll
    for (int nf = 0; nf < 4; ++nf)
      b[nf] = *reinterpret_cast<const bf16x8*>(&Bs[(wc * 64 + nf * 16 + lr) * 32 + lk]);
#pragma unroll
    for (int mf = 0; mf < 4; ++mf)
#pragma unroll
      for (int nf = 0; nf < 4; ++nf)
        acc[mf][nf] = __builtin_amdgcn_mfma_f32_16x16x32_bf16(a[mf], b[nf], acc[mf][nf], 0, 0, 0);
    __syncthreads();
  }

#pragma unroll
  for (int mf = 0; mf < 4; ++mf) {
#pragma unroll
    for (int nf = 0; nf < 4; ++nf) {
      const int col = n0 + wc * 64 + nf * 16 + lr;
      const float bv = bias[col];
#pragma unroll
      for (int j = 0; j < 4; ++j) {
        const int row = m0 + wr * 64 + mf * 16 + (l >> 4) * 4 + j;
        const size_t idx = (size_t)row * N + col;
        const float vv = acc[mf][nf][j] + bv;
        if (EPI == 0)
          ((u16*)Cout)[idx] = f2bf(vv);
        else if (EPI == 1)
          ((float*)Cout)[idx] = vv + res[idx];
        else
          ((u16*)Cout)[idx] = f2bf(fmaxf(vv, 0.f));
      }
    }
  }
}

// ---------- flash attention fwd, LDS-staged K/V, 128 q-rows/block ----------
// qkv: [B*S][3072] bf16 fused (Q at +0, K at +1024). vt: [B][1024][2048] bf16.
__global__ __launch_bounds__(256) void attn_fwd2(
    const u16* __restrict__ qkv, const u16* __restrict__ vt,
    const int* __restrict__ mask, u16* __restrict__ ctx) {
  __shared__ u16 Ks[2][64 * 64];
  __shared__ u16 Vs[2][64 * 64];
  __shared__ u16 plds[4][32][72];   // per-wave P tile, stride 144B (<=2-way)
  const int tid = threadIdx.x;
  const int l = tid & 63;
  const int w = tid >> 6;
  const int b = blockIdx.y >> 4, h = blockIdx.y & 15;
  const int r0 = blockIdx.x * 128 + w * 32;
  const int lr = l & 15, lg = l >> 4, lk = lg * 8;

  const u16* qb = qkv + (size_t)b * 2048 * 3072 + h * 64;
  const u16* kp = qb + 1024;
  const u16* vb = vt + ((size_t)b * 1024 + h * 64) * 2048;
  const int* mb = mask + (size_t)b * 2048;

  // Q fragments held in registers for the whole kernel
  bf16x8 aq[2][2];
#pragma unroll
  for (int m = 0; m < 2; ++m)
#pragma unroll
    for (int ks = 0; ks < 2; ++ks)
      aq[m][ks] = *reinterpret_cast<const bf16x8*>(
          qb + (size_t)(r0 + m * 16 + lr) * 3072 + ks * 32 + lk);

  float mrun[2][4], lrun[2][4];
  f32x4 o[2][4];
#pragma unroll
  for (int m = 0; m < 2; ++m)
#pragma unroll
    for (int j = 0; j < 4; ++j) { mrun[m][j] = -1e30f; lrun[m][j] = 0.f; }
#pragma unroll
  for (int m = 0; m < 2; ++m)
#pragma unroll
    for (int d = 0; d < 4; ++d) o[m][d] = f32x4{0.f, 0.f, 0.f, 0.f};

  // staging pointers: chunk ci covers lds [ci*16B]; row=ci>>3, swizzled source chunk
  const u16* kS[2];
  const u16* vS[2];
#pragma unroll
  for (int i = 0; i < 2; ++i) {
    const int ci = tid + i * 256;
    const int row = ci >> 3, cc = ci & 7;
    const int sc = cc ^ (row & 7);
    kS[i] = kp + (size_t)row * 3072 + sc * 8;
    vS[i] = vb + (size_t)row * 2048 + sc * 8;
  }

  // prologue: stage tile 0 into buffer 0
#pragma unroll
  for (int i = 0; i < 2; ++i) {
    const int ci8 = (tid + i * 256) * 8;
    gld_lds16(kS[i], &Ks[0][ci8]);
    gld_lds16(vS[i], &Vs[0][ci8]);
  }
  asm volatile("s_waitcnt vmcnt(0)" ::: "memory");
  __syncthreads();

  int cur = 0;
  for (int t = 0; t < 32; ++t) {
    const int kb0 = t * 64;
    // prefetch next tile into the other buffer
    if (t + 1 < 32) {
      const int nb = kb0 + 64;
#pragma unroll
      for (int i = 0; i < 2; ++i) {
        const int ci8 = (tid + i * 256) * 8;
        gld_lds16(kS[i] + (size_t)nb * 3072, &Ks[cur ^ 1][ci8]);
        gld_lds16(vS[i] + nb, &Vs[cur ^ 1][ci8]);
      }
    }

    // ---- QK^T from LDS (swizzled reads, conflict-free) ----
    f32x4 s[2][4];
#pragma unroll
    for (int cf = 0; cf < 4; ++cf) {
      const int krow = cf * 16 + lr;
      const int ch0 = (0 * 4 + lg) ^ (krow & 7);
      const int ch1 = (1 * 4 + lg) ^ (krow & 7);
      const bf16x8 bk0 = *reinterpret_cast<const bf16x8*>(&Ks[cur][krow * 64 + ch0 * 8]);
      const bf16x8 bk1 = *reinterpret_cast<const bf16x8*>(&Ks[cur][krow * 64 + ch1 * 8]);
#pragma unroll
      for (int m = 0; m < 2; ++m) {
        f32x4 acc = __builtin_amdgcn_mfma_f32_16x16x32_bf16(aq[m][0], bk0,
                                                            f32x4{0.f, 0.f, 0.f, 0.f}, 0, 0, 0);
        acc = __builtin_amdgcn_mfma_f32_16x16x32_bf16(aq[m][1], bk1, acc, 0, 0, 0);
        s[m][cf] = acc;
      }
    }

    // ---- mask + scale ----
#pragma unroll
    for (int cf = 0; cf < 4; ++cf) {
      const bool live = (mb[kb0 + cf * 16 + lr] != 0);
#pragma unroll
      for (int m = 0; m < 2; ++m)
#pragma unroll
        for (int j = 0; j < 4; ++j)
          s[m][cf][j] = live ? s[m][cf][j] * 0.125f : -1e9f;
    }

    // ---- online softmax (per 16-lane group; q-row = m*16 + lg*4 + j) ----
#pragma unroll
    for (int m = 0; m < 2; ++m) {
#pragma unroll
      for (int j = 0; j < 4; ++j) {
        float pm = fmaxf(fmaxf(s[m][0][j], s[m][1][j]), fmaxf(s[m][2][j], s[m][3][j]));
#pragma unroll
        for (int off = 8; off > 0; off >>= 1) pm = fmaxf(pm, __shfl_xor(pm, off));
        const float mn = fmaxf(mrun[m][j], pm);
        const float corr = __expf(mrun[m][j] - mn);
        mrun[m][j] = mn;
        float rs = 0.f;
#pragma unroll
        for (int cf = 0; cf < 4; ++cf) {
          const float p = __expf(s[m][cf][j] - mn);
          s[m][cf][j] = p;
          rs += p;
        }
#pragma unroll
        for (int off = 8; off > 0; off >>= 1) rs += __shfl_xor(rs, off);
        lrun[m][j] = lrun[m][j] * corr + rs;
#pragma unroll
        for (int d = 0; d < 4; ++d) o[m][d][j] *= corr;
      }
    }

    // ---- P -> LDS (bf16), re-read as A fragments (wave-private) ----
#pragma unroll
    for (int m = 0; m < 2; ++m)
#pragma unroll
      for (int cf = 0; cf < 4; ++cf)
#pragma unroll
        for (int j = 0; j < 4; ++j)
          plds[w][m * 16 + lg * 4 + j][cf * 16 + lr] = f2bf(s[m][cf][j]);
    asm volatile("s_waitcnt lgkmcnt(0)" ::: "memory");
    __builtin_amdgcn_sched_barrier(0);
    bf16x8 pa[2][2];
#pragma unroll
    for (int m = 0; m < 2; ++m)
#pragma unroll
      for (int ks = 0; ks < 2; ++ks)
        pa[m][ks] = *reinterpret_cast<const bf16x8*>(&plds[w][m * 16 + lr][ks * 32 + lk]);

    // ---- PV from LDS V^T tile ----
#pragma unroll
    for (int d = 0; d < 4; ++d) {
      const int vrow = d * 16 + lr;
      const int ch0 = (0 * 4 + lg) ^ (vrow & 7);
      const int ch1 = (1 * 4 + lg) ^ (vrow & 7);
      const bf16x8 bv0 = *reinterpret_cast<const bf16x8*>(&Vs[cur][vrow * 64 + ch0 * 8]);
      const bf16x8 bv1 = *reinterpret_cast<const bf16x8*>(&Vs[cur][vrow * 64 + ch1 * 8]);
#pragma unroll
      for (int m = 0; m < 2; ++m) {
        o[m][d] = __builtin_amdgcn_mfma_f32_16x16x32_bf16(pa[m][0], bv0, o[m][d], 0, 0, 0);
        o[m][d] = __builtin_amdgcn_mfma_f32_16x16x32_bf16(pa[m][1], bv1, o[m][d], 0, 0, 0);
      }
    }

    asm volatile("s_waitcnt vmcnt(0)" ::: "memory");
    __syncthreads();
    cur ^= 1;
  }

  // epilogue
#pragma unroll
  for (int m = 0; m < 2; ++m)
#pragma unroll
    for (int d = 0; d < 4; ++d)
#pragma unroll
      for (int j = 0; j < 4; ++j) {
        const int row = r0 + m * 16 + lg * 4 + j;
        const float val = o[m][d][j] / lrun[m][j];
        ctx[((size_t)b * 2048 + row) * 1024 + h * 64 + d * 16 + lr] = f2bf(val);
      }
}

// ---------- launch ----------
extern "C" void kernel_launch(void* const* d_in, const int* in_sizes, int n_in,
                              void* d_out, int out_size, void* d_ws, size_t ws_size,
                              hipStream_t stream) {
  const float* x = (const float*)d_in[0];
  const int* mask = (const int*)d_in[1];
  const float* wq = (const float*)d_in[2];
  const float* bq = (const float*)d_in[3];
  const float* wk = (const float*)d_in[4];
  const float* bk = (const float*)d_in[5];
  const float* wv = (const float*)d_in[6];
  const float* bv = (const float*)d_in[7];
  const float* wo = (const float*)d_in[8];
  const float* bo = (const float*)d_in[9];
  const float* w1 = (const float*)d_in[10];
  const float* b1 = (const float*)d_in[11];
  const float* w2 = (const float*)d_in[12];
  const float* b2 = (const float*)d_in[13];
  const float* ln1a = (const float*)d_in[14];
  const float* ln1b = (const float*)d_in[15];
  const float* ln2a = (const float*)d_in[16];
  const float* ln2b = (const float*)d_in[17];

  char* ws = (char*)d_ws;
  const size_t MB = 1024ull * 1024ull;
  // layout (peak use 137 MB):
  u16* WTQKV = (u16*)(ws + 0 * MB);    // [3072][1024] bf16, 6MB
  u16* WTO = (u16*)(ws + 6 * MB);      // 2MB
  u16* W1T = (u16*)(ws + 8 * MB);      // [4096][1024], 8MB
  u16* W2T = (u16*)(ws + 16 * MB);     // [1024][4096], 8MB
  float* BQKV = (float*)(ws + 24 * MB);
  u16* QKV = (u16*)(ws + 25 * MB);     // [8192][3072] bf16, 48MB (25-73)
  u16* XN = (u16*)(ws + 73 * MB);      // 16MB (73-89); dead after QKV gemm
  u16* VT = (u16*)(ws + 73 * MB);      // reuses XN region (73-89)
  u16* CTX = (u16*)(ws + 89 * MB);     // 16MB (89-105)
  float* X2 = (float*)(ws + 25 * MB);  // 32MB (25-57), overwrites QKV after attn
  u16* XN2 = (u16*)(ws + 57 * MB);     // 16MB (57-73)
  u16* H1 = (u16*)(ws + 73 * MB);      // [8192][4096] bf16, 64MB (73-137)

  dim3 bt(32, 8);
  // weights: bf16 + transpose (WQ|WK|WV stacked -> [3072][1024])
  wcvt_t<<<dim3(32, 32), bt, 0, stream>>>(wq, WTQKV, 1024, 1024);
  wcvt_t<<<dim3(32, 32), bt, 0, stream>>>(wk, WTQKV + 1024 * 1024, 1024, 1024);
  wcvt_t<<<dim3(32, 32), bt, 0, stream>>>(wv, WTQKV + 2048 * 1024, 1024, 1024);
  wcvt_t<<<dim3(32, 32), bt, 0, stream>>>(wo, WTO, 1024, 1024);
  wcvt_t<<<dim3(128, 32), bt, 0, stream>>>(w1, W1T, 1024, 4096);
  wcvt_t<<<dim3(32, 128), bt, 0, stream>>>(w2, W2T, 4096, 1024);
  pack_bias<<<dim3(12), 256, 0, stream>>>(bq, bk, bv, BQKV);

  // LN1
  ln_kernel<<<8192, 256, 0, stream>>>(x, XN, ln1a, ln1b);
  // fused QKV projection: [8192][3072]
  gemm_bt<0><<<dim3(24, 64), 256, 0, stream>>>(XN, WTQKV, BQKV, nullptr, QKV, 8192, 3072, 1024);
  // V transpose for PV fragments (V at col offset 2048, row stride 3072)
  vtrans<<<dim3(32, 64, 4), bt, 0, stream>>>(QKV + 2048, VT, 3072);
  // attention
  attn_fwd2<<<dim3(16, 64), 256, 0, stream>>>(QKV, VT, mask, CTX);
  // O-proj + residual (fp32)
  gemm_bt<1><<<dim3(8, 64), 256, 0, stream>>>(CTX, WTO, bo, x, X2, 8192, 1024, 1024);
  // LN2
  ln_kernel<<<8192, 256, 0, stream>>>(X2, XN2, ln2a, ln2b);
  // FFN
  gemm_bt<2><<<dim3(32, 64), 256, 0, stream>>>(XN2, W1T, b1, nullptr, H1, 8192, 4096, 1024);
  gemm_bt<1><<<dim3(8, 64), 256, 0, stream>>>(H1, W2T, b2, X2, (float*)d_out, 8192, 1024, 4096);
}

// Round 4
// 537.066 us; speedup vs baseline: 1.5579x; 1.1456x over previous
//
#include <hip/hip_runtime.h>

typedef unsigned short u16;
typedef __bf16 bf16x8 __attribute__((ext_vector_type(8)));
typedef float f32x4 __attribute__((ext_vector_type(4)));

// ---------- helpers ----------
__device__ __forceinline__ u16 f2bf(float f) {
  unsigned u = __builtin_bit_cast(unsigned, f);
  unsigned lsb = (u >> 16) & 1u;
  u += 0x7fffu + lsb;                 // round-to-nearest-even
  return (u16)(u >> 16);
}

__device__ __forceinline__ unsigned pack2bf(float lo, float hi) {
  return (unsigned)f2bf(lo) | ((unsigned)f2bf(hi) << 16);
}

__device__ __forceinline__ void gld_lds16(const u16* g, u16* l) {
  __builtin_amdgcn_global_load_lds(
      (__attribute__((address_space(1))) void*)g,
      (__attribute__((address_space(3))) void*)l, 16, 0, 0);
}

// ---------- LayerNorm ----------
__global__ __launch_bounds__(256) void ln_kernel(
    const float* __restrict__ x, u16* __restrict__ out,
    const float* __restrict__ alpha_p, const float* __restrict__ beta_p) {
  const int row = blockIdx.x;
  const int t = threadIdx.x;
  const float4 v = reinterpret_cast<const float4*>(x + (size_t)row * 1024)[t];
  float s = v.x + v.y + v.z + v.w;
  float sq = v.x * v.x + v.y * v.y + v.z * v.z + v.w * v.w;
#pragma unroll
  for (int off = 32; off > 0; off >>= 1) {
    s += __shfl_down(s, off);
    sq += __shfl_down(sq, off);
  }
  __shared__ float red[8];
  const int w = t >> 6;
  if ((t & 63) == 0) { red[w] = s; red[4 + w] = sq; }
  __syncthreads();
  const float ts = red[0] + red[1] + red[2] + red[3];
  const float tq = red[4] + red[5] + red[6] + red[7];
  const float mean = ts * (1.0f / 1024.0f);
  float var = (tq - ts * mean) * (1.0f / 1023.0f);
  var = fmaxf(var, 0.0f);
  const float rden = 1.0f / (sqrtf(var) + 1e-5f);
  const float a = alpha_p[0], bb = beta_p[0];
  ushort4 ov;
  ov.x = f2bf(a * (v.x - mean) * rden + bb);
  ov.y = f2bf(a * (v.y - mean) * rden + bb);
  ov.z = f2bf(a * (v.z - mean) * rden + bb);
  ov.w = f2bf(a * (v.w - mean) * rden + bb);
  reinterpret_cast<ushort4*>(out + (size_t)row * 1024)[t] = ov;
}

// ---------- weight convert fp32 [K][N] -> bf16 transposed [N][K] ----------
__global__ __launch_bounds__(256) void wcvt_t(
    const float* __restrict__ w, u16* __restrict__ wt, int K, int N) {
  __shared__ float tile[32][33];
  const int n0 = blockIdx.x * 32, k0 = blockIdx.y * 32;
  const int tx = threadIdx.x, ty = threadIdx.y;
#pragma unroll
  for (int i = 0; i < 4; ++i)
    tile[ty + i * 8][tx] = w[(size_t)(k0 + ty + i * 8) * N + n0 + tx];
  __syncthreads();
#pragma unroll
  for (int i = 0; i < 4; ++i)
    wt[(size_t)(n0 + ty + i * 8) * K + k0 + tx] = f2bf(tile[tx][ty + i * 8]);
}

// ---------- bias concat + mask bias ----------
__global__ __launch_bounds__(256) void pack_bias(
    const float* __restrict__ a, const float* __restrict__ b,
    const float* __restrict__ c, float* __restrict__ o) {
  const int i = blockIdx.x * 256 + threadIdx.x;
  o[i] = (i < 1024) ? a[i] : ((i < 2048) ? b[i - 1024] : c[i - 2048]);
}

__global__ __launch_bounds__(256) void mk_mbias(
    const int* __restrict__ mask, float* __restrict__ mb) {
  const int i = blockIdx.x * 256 + threadIdx.x;
  mb[i] = mask[i] ? 0.f : -1.4427e9f;   // -1e9 * log2(e)
}

// ---------- bf16 transpose per batch: v [B][S][vstride] -> vt [B][1024][2048] ----------
__global__ __launch_bounds__(256) void vtrans(
    const u16* __restrict__ v, u16* __restrict__ vt, int vstride) {
  __shared__ u16 tile[32][33];
  const int d0 = blockIdx.x * 32, s0 = blockIdx.y * 32, b = blockIdx.z;
  const int tx = threadIdx.x, ty = threadIdx.y;
  const u16* vb = v + (size_t)b * 2048 * vstride;
  u16* vo = vt + (size_t)b * 1024 * 2048;
#pragma unroll
  for (int i = 0; i < 4; ++i)
    tile[ty + i * 8][tx] = vb[(size_t)(s0 + ty + i * 8) * vstride + d0 + tx];
  __syncthreads();
#pragma unroll
  for (int i = 0; i < 4; ++i)
    vo[(size_t)(d0 + ty + i * 8) * 2048 + s0 + tx] = tile[tx][ty + i * 8];
}

// ---------- GEMM (m97 structure + XCD swizzle) ----------
// EPI 0: bf16 out.  EPI 1: f32 out = acc+bias+res.  EPI 2: bf16 relu out.
template <int EPI>
__global__ __launch_bounds__(256) void gemm_bt(
    const u16* __restrict__ A, const u16* __restrict__ Bt,
    const float* __restrict__ bias, const float* __restrict__ res,
    void* __restrict__ Cout, int M, int N, int K) {
  __shared__ u16 As[128 * 32];
  __shared__ u16 Bs[128 * 32];
  const int tid = threadIdx.x;
  const int l = tid & 63;
  const int w = tid >> 6;
  const int wr = w >> 1, wc = w & 1;
  // bijective XCD swizzle (all grids have nwg % 8 == 0)
  const int gx = gridDim.x;
  int id = blockIdx.y * gx + blockIdx.x;
  const int nwg = gx * gridDim.y;
  id = (id & 7) * (nwg >> 3) + (id >> 3);
  const int n0 = (id % gx) * 128;
  const int m0 = (id / gx) * 128;
  const int lr = l & 15, lk = (l >> 4) * 8;

  f32x4 acc[4][4];
#pragma unroll
  for (int i = 0; i < 4; ++i)
#pragma unroll
    for (int j = 0; j < 4; ++j) acc[i][j] = f32x4{0.f, 0.f, 0.f, 0.f};

  const int srow = tid >> 2;
  const int scol = (tid & 3) * 8;
  const u16* gA0 = A + (size_t)(m0 + srow) * K + scol;
  const u16* gA1 = A + (size_t)(m0 + 64 + srow) * K + scol;
  const u16* gB0 = Bt + (size_t)(n0 + srow) * K + scol;
  const u16* gB1 = Bt + (size_t)(n0 + 64 + srow) * K + scol;
  u16* lA0 = &As[tid * 8];
  u16* lA1 = &As[2048 + tid * 8];
  u16* lB0 = &Bs[tid * 8];
  u16* lB1 = &Bs[2048 + tid * 8];

  for (int k0 = 0; k0 < K; k0 += 32) {
    gld_lds16(gA0 + k0, lA0);
    gld_lds16(gA1 + k0, lA1);
    gld_lds16(gB0 + k0, lB0);
    gld_lds16(gB1 + k0, lB1);
    __syncthreads();
    bf16x8 a[4], b[4];
#pragma unroll
    for (int mf = 0; mf < 4; ++mf)
      a[mf] = *reinterpret_cast<const bf16x8*>(&As[(wr * 64 + mf * 16 + lr) * 32 + lk]);
#pragma unroll
    for (int nf = 0; nf < 4; ++nf)
      b[nf] = *reinterpret_cast<const bf16x8*>(&Bs[(wc * 64 + nf * 16 + lr) * 32 + lk]);
#pragma unroll
    for (int mf = 0; mf < 4; ++mf)
#pragma unroll
      for (int nf = 0; nf < 4; ++nf)
        acc[mf][nf] = __builtin_amdgcn_mfma_f32_16x16x32_bf16(a[mf], b[nf], acc[mf][nf], 0, 0, 0);
    __syncthreads();
  }

#pragma unroll
  for (int mf = 0; mf < 4; ++mf) {
#pragma unroll
    for (int nf = 0; nf < 4; ++nf) {
      const int col = n0 + wc * 64 + nf * 16 + lr;
      const float bv = bias[col];
#pragma unroll
      for (int j = 0; j < 4; ++j) {
        const int row = m0 + wr * 64 + mf * 16 + (l >> 4) * 4 + j;
        const size_t idx = (size_t)row * N + col;
        const float vv = acc[mf][nf][j] + bv;
        if (EPI == 0)
          ((u16*)Cout)[idx] = f2bf(vv);
        else if (EPI == 1)
          ((float*)Cout)[idx] = vv + res[idx];
        else
          ((u16*)Cout)[idx] = f2bf(fmaxf(vv, 0.f));
      }
    }
  }
}

// ---------- flash attention, swapped QK^T, in-register softmax ----------
// qkv: [B*S][3072] bf16 (Q +0, K +1024). vt: [B][1024][2048] bf16. mbias: [B][2048] f32 (log2 domain).
__global__ __launch_bounds__(256, 4) void attn_fwd3(
    const u16* __restrict__ qkv, const u16* __restrict__ vt,
    const float* __restrict__ mbias, u16* __restrict__ ctx) {
  __shared__ u16 Ks[2][64 * 64];
  __shared__ u16 Vs[2][64 * 64];
  const int tid = threadIdx.x;
  const int l = tid & 63;
  const int w = tid >> 6;
  const int b = blockIdx.y >> 4, h = blockIdx.y & 15;
  const int r0 = blockIdx.x * 128 + w * 32;
  const int lr = l & 15, lg = l >> 4;
  const float SCL2 = 0.125f * 1.4426950408889634f;  // exp2 domain

  const u16* qb = qkv + (size_t)b * 2048 * 3072 + h * 64;
  const u16* kp = qb + 1024;
  const u16* vb = vt + ((size_t)b * 1024 + h * 64) * 2048;
  const float* mb = mbias + (size_t)b * 2048;

  // Q as B-fragment: Q[q = r0+m*16+lr][dk = ks*32 + lg*8 + e]
  bf16x8 qf[2][2];
#pragma unroll
  for (int m = 0; m < 2; ++m)
#pragma unroll
    for (int ks = 0; ks < 2; ++ks)
      qf[m][ks] = *reinterpret_cast<const bf16x8*>(
          qb + (size_t)(r0 + m * 16 + lr) * 3072 + ks * 32 + lg * 8);

  float mrun[2] = {-1e30f, -1e30f};
  float lrun[2] = {0.f, 0.f};
  f32x4 o[2][4];
#pragma unroll
  for (int m = 0; m < 2; ++m)
#pragma unroll
    for (int d = 0; d < 4; ++d) o[m][d] = f32x4{0.f, 0.f, 0.f, 0.f};

  // staging: LDS linear dest, pre-swizzled global source (chunk ^= row&7)
  const u16* kS[2];
  const u16* vS[2];
#pragma unroll
  for (int i = 0; i < 2; ++i) {
    const int ci = tid + i * 256;
    const int row = ci >> 3, cc = ci & 7;
    const int sc = cc ^ (row & 7);
    kS[i] = kp + (size_t)row * 3072 + sc * 8;
    vS[i] = vb + (size_t)row * 2048 + sc * 8;
  }
#pragma unroll
  for (int i = 0; i < 2; ++i) {
    const int ci8 = (tid + i * 256) * 8;
    gld_lds16(kS[i], &Ks[0][ci8]);
    gld_lds16(vS[i], &Vs[0][ci8]);
  }
  asm volatile("s_waitcnt vmcnt(0)" ::: "memory");
  __syncthreads();

  union U8 { unsigned u[4]; bf16x8 v; };

  int cur = 0;
  for (int t = 0; t < 32; ++t) {
    const int kb0 = t * 64;
    if (t + 1 < 32) {
      const int nb = kb0 + 64;
#pragma unroll
      for (int i = 0; i < 2; ++i) {
        const int ci8 = (tid + i * 256) * 8;
        gld_lds16(kS[i] + (size_t)nb * 3072, &Ks[cur ^ 1][ci8]);
        gld_lds16(vS[i] + nb, &Vs[cur ^ 1][ci8]);
      }
    }

    // ---- QK^T swapped: st[m][cf] = P^T tile, lane holds kv=cf*16+lg*4+j, q=m*16+lr ----
    f32x4 st[2][4];
    __builtin_amdgcn_s_setprio(1);
#pragma unroll
    for (int cf = 0; cf < 4; ++cf) {
      const int krow = cf * 16 + lr;
      const int ch0 = lg ^ (krow & 7);
      const int ch1 = (4 + lg) ^ (krow & 7);
      const bf16x8 kf0 = *reinterpret_cast<const bf16x8*>(&Ks[cur][krow * 64 + ch0 * 8]);
      const bf16x8 kf1 = *reinterpret_cast<const bf16x8*>(&Ks[cur][krow * 64 + ch1 * 8]);
#pragma unroll
      for (int m = 0; m < 2; ++m) {
        f32x4 acc = __builtin_amdgcn_mfma_f32_16x16x32_bf16(kf0, qf[m][0],
                                                            f32x4{0.f, 0.f, 0.f, 0.f}, 0, 0, 0);
        st[m][cf] = __builtin_amdgcn_mfma_f32_16x16x32_bf16(kf1, qf[m][1], acc, 0, 0, 0);
      }
    }
    __builtin_amdgcn_s_setprio(0);

    // ---- scale + additive mask (log2 domain) ----
#pragma unroll
    for (int cf = 0; cf < 4; ++cf) {
      const float4 m4 = *reinterpret_cast<const float4*>(mb + kb0 + cf * 16 + lg * 4);
#pragma unroll
      for (int m = 0; m < 2; ++m) {
        st[m][cf][0] = st[m][cf][0] * SCL2 + m4.x;
        st[m][cf][1] = st[m][cf][1] * SCL2 + m4.y;
        st[m][cf][2] = st[m][cf][2] * SCL2 + m4.z;
        st[m][cf][3] = st[m][cf][3] * SCL2 + m4.w;
      }
    }

    // ---- per-m: in-register softmax + P->bf16 exchange ----
    bf16x8 paA[2], paB[2];
#pragma unroll
    for (int m = 0; m < 2; ++m) {
      float pm = fmaxf(fmaxf(st[m][0][0], st[m][0][1]), fmaxf(st[m][0][2], st[m][0][3]));
#pragma unroll
      for (int cf = 1; cf < 4; ++cf)
        pm = fmaxf(pm, fmaxf(fmaxf(st[m][cf][0], st[m][cf][1]),
                             fmaxf(st[m][cf][2], st[m][cf][3])));
      pm = fmaxf(pm, __shfl_xor(pm, 16));
      pm = fmaxf(pm, __shfl_xor(pm, 32));
      if (__any(pm > mrun[m] + 8.f)) {          // defer-max (T13)
        const float mn = fmaxf(mrun[m], pm);
        const float corr = exp2f(mrun[m] - mn);
        mrun[m] = mn;
        lrun[m] *= corr;
#pragma unroll
        for (int d = 0; d < 4; ++d)
#pragma unroll
          for (int j = 0; j < 4; ++j) o[m][d][j] *= corr;
      }
      float rs = 0.f;
#pragma unroll
      for (int cf = 0; cf < 4; ++cf)
#pragma unroll
        for (int j = 0; j < 4; ++j) {
          const float p = exp2f(st[m][cf][j] - mrun[m]);
          st[m][cf][j] = p;
          rs += p;
        }
      rs += __shfl_xor(rs, 16);
      rs += __shfl_xor(rs, 32);
      lrun[m] += rs;

      // pack to bf16 pairs: pk[cf][wp] = kv (16cf+4lg+2wp, +1)
      unsigned pk[4][2];
#pragma unroll
      for (int cf = 0; cf < 4; ++cf)
#pragma unroll
        for (int wp = 0; wp < 2; ++wp)
          pk[cf][wp] = pack2bf(st[m][cf][2 * wp], st[m][cf][2 * wp + 1]);

      // exchange: dest lane lg needs kv = 32ks+8lg+2w from lane (2lg+(w>>1))&3,
      // word pk[2ks + (lg>>1)][w&1]
      U8 a0, a1;
#pragma unroll
      for (int c = 0; c < 2; ++c) {
        const int src = lr + 16 * ((2 * lg + c) & 3);
#pragma unroll
        for (int wp = 0; wp < 2; ++wp) {
          const int v00 = __shfl((int)pk[0][wp], src);
          const int v01 = __shfl((int)pk[1][wp], src);
          const int v10 = __shfl((int)pk[2][wp], src);
          const int v11 = __shfl((int)pk[3][wp], src);
          a0.u[2 * c + wp] = (unsigned)((lg < 2) ? v00 : v01);
          a1.u[2 * c + wp] = (unsigned)((lg < 2) ? v10 : v11);
        }
      }
      paA[m] = a0.v;
      paB[m] = a1.v;
    }

    // ---- PV: O^T += V^T_tile · P^T ----
    __builtin_amdgcn_s_setprio(1);
#pragma unroll
    for (int df = 0; df < 4; ++df) {
      const int vrow = df * 16 + lr;
      const int ch0 = lg ^ (vrow & 7);
      const int ch1 = (4 + lg) ^ (vrow & 7);
      const bf16x8 vf0 = *reinterpret_cast<const bf16x8*>(&Vs[cur][vrow * 64 + ch0 * 8]);
      const bf16x8 vf1 = *reinterpret_cast<const bf16x8*>(&Vs[cur][vrow * 64 + ch1 * 8]);
#pragma unroll
      for (int m = 0; m < 2; ++m) {
        o[m][df] = __builtin_amdgcn_mfma_f32_16x16x32_bf16(vf0, paA[m], o[m][df], 0, 0, 0);
        o[m][df] = __builtin_amdgcn_mfma_f32_16x16x32_bf16(vf1, paB[m], o[m][df], 0, 0, 0);
      }
    }
    __builtin_amdgcn_s_setprio(0);

    asm volatile("s_waitcnt vmcnt(0)" ::: "memory");
    __syncthreads();
    cur ^= 1;
  }

  // ---- epilogue: O^T[d][q], packed 8B stores ----
#pragma unroll
  for (int m = 0; m < 2; ++m) {
    const float rdiv = 1.f / lrun[m];
    const size_t rowbase = ((size_t)b * 2048 + r0 + m * 16 + lr) * 1024 + h * 64;
#pragma unroll
    for (int df = 0; df < 4; ++df) {
      ushort4 s4;
      s4.x = f2bf(o[m][df][0] * rdiv);
      s4.y = f2bf(o[m][df][1] * rdiv);
      s4.z = f2bf(o[m][df][2] * rdiv);
      s4.w = f2bf(o[m][df][3] * rdiv);
      *reinterpret_cast<ushort4*>(ctx + rowbase + df * 16 + lg * 4) = s4;
    }
  }
}

// ---------- launch ----------
extern "C" void kernel_launch(void* const* d_in, const int* in_sizes, int n_in,
                              void* d_out, int out_size, void* d_ws, size_t ws_size,
                              hipStream_t stream) {
  const float* x = (const float*)d_in[0];
  const int* mask = (const int*)d_in[1];
  const float* wq = (const float*)d_in[2];
  const float* bq = (const float*)d_in[3];
  const float* wk = (const float*)d_in[4];
  const float* bk = (const float*)d_in[5];
  const float* wv = (const float*)d_in[6];
  const float* bv = (const float*)d_in[7];
  const float* wo = (const float*)d_in[8];
  const float* bo = (const float*)d_in[9];
  const float* w1 = (const float*)d_in[10];
  const float* b1 = (const float*)d_in[11];
  const float* w2 = (const float*)d_in[12];
  const float* b2 = (const float*)d_in[13];
  const float* ln1a = (const float*)d_in[14];
  const float* ln1b = (const float*)d_in[15];
  const float* ln2a = (const float*)d_in[16];
  const float* ln2b = (const float*)d_in[17];

  char* ws = (char*)d_ws;
  const size_t MB = 1024ull * 1024ull;
  u16* WTQKV = (u16*)(ws + 0 * MB);    // [3072][1024] bf16, 6MB
  u16* WTO = (u16*)(ws + 6 * MB);      // 2MB
  u16* W1T = (u16*)(ws + 8 * MB);      // [4096][1024], 8MB
  u16* W2T = (u16*)(ws + 16 * MB);     // [1024][4096], 8MB
  float* BQKV = (float*)(ws + 24 * MB);            // 12KB
  float* MBIAS = (float*)(ws + 24 * MB + 65536);   // 32KB
  u16* QKV = (u16*)(ws + 25 * MB);     // [8192][3072] bf16, 48MB (25-73)
  u16* XN = (u16*)(ws + 73 * MB);      // 16MB (73-89); dead after QKV gemm
  u16* VT = (u16*)(ws + 73 * MB);      // reuses XN region
  u16* CTX = (u16*)(ws + 89 * MB);     // 16MB (89-105)
  float* X2 = (float*)(ws + 25 * MB);  // 32MB, overwrites QKV after attn
  u16* XN2 = (u16*)(ws + 57 * MB);     // 16MB (57-73)
  u16* H1 = (u16*)(ws + 73 * MB);      // [8192][4096] bf16, 64MB (73-137)

  dim3 bt(32, 8);
  wcvt_t<<<dim3(32, 32), bt, 0, stream>>>(wq, WTQKV, 1024, 1024);
  wcvt_t<<<dim3(32, 32), bt, 0, stream>>>(wk, WTQKV + 1024 * 1024, 1024, 1024);
  wcvt_t<<<dim3(32, 32), bt, 0, stream>>>(wv, WTQKV + 2048 * 1024, 1024, 1024);
  wcvt_t<<<dim3(32, 32), bt, 0, stream>>>(wo, WTO, 1024, 1024);
  wcvt_t<<<dim3(128, 32), bt, 0, stream>>>(w1, W1T, 1024, 4096);
  wcvt_t<<<dim3(32, 128), bt, 0, stream>>>(w2, W2T, 4096, 1024);
  pack_bias<<<dim3(12), 256, 0, stream>>>(bq, bk, bv, BQKV);
  mk_mbias<<<dim3(32), 256, 0, stream>>>(mask, MBIAS);

  ln_kernel<<<8192, 256, 0, stream>>>(x, XN, ln1a, ln1b);
  gemm_bt<0><<<dim3(24, 64), 256, 0, stream>>>(XN, WTQKV, BQKV, nullptr, QKV, 8192, 3072, 1024);
  vtrans<<<dim3(32, 64, 4), bt, 0, stream>>>(QKV + 2048, VT, 3072);
  attn_fwd3<<<dim3(16, 64), 256, 0, stream>>>(QKV, VT, MBIAS, CTX);
  gemm_bt<1><<<dim3(8, 64), 256, 0, stream>>>(CTX, WTO, bo, x, X2, 8192, 1024, 1024);
  ln_kernel<<<8192, 256, 0, stream>>>(X2, XN2, ln2a, ln2b);
  gemm_bt<2><<<dim3(32, 64), 256, 0, stream>>>(XN2, W1T, b1, nullptr, H1, 8192, 4096, 1024);
  gemm_bt<1><<<dim3(8, 64), 256, 0, stream>>>(H1, W2T, b2, X2, (float*)d_out, 8192, 1024, 4096);
}

// Round 5
// 506.853 us; speedup vs baseline: 1.6508x; 1.0596x over previous
//
#include <hip/hip_runtime.h>

typedef unsigned short u16;
typedef __bf16 bf16x8 __attribute__((ext_vector_type(8)));
typedef float f32x4 __attribute__((ext_vector_type(4)));

// ---------- helpers ----------
__device__ __forceinline__ u16 f2bf(float f) {
  unsigned u = __builtin_bit_cast(unsigned, f);
  unsigned lsb = (u >> 16) & 1u;
  u += 0x7fffu + lsb;                 // round-to-nearest-even
  return (u16)(u >> 16);
}

// D.lo = bf16(lo), D.hi = bf16(hi) — single VALU op (vs ~9 for manual pair)
__device__ __forceinline__ unsigned cvt_pk_bf16(float lo, float hi) {
  unsigned r;
  asm("v_cvt_pk_bf16_f32 %0, %1, %2" : "=v"(r) : "v"(lo), "v"(hi));
  return r;
}

__device__ __forceinline__ void gld_lds16(const u16* g, u16* l) {
  __builtin_amdgcn_global_load_lds(
      (__attribute__((address_space(1))) void*)g,
      (__attribute__((address_space(3))) void*)l, 16, 0, 0);
}

// ---------- LayerNorm ----------
__global__ __launch_bounds__(256) void ln_kernel(
    const float* __restrict__ x, u16* __restrict__ out,
    const float* __restrict__ alpha_p, const float* __restrict__ beta_p) {
  const int row = blockIdx.x;
  const int t = threadIdx.x;
  const float4 v = reinterpret_cast<const float4*>(x + (size_t)row * 1024)[t];
  float s = v.x + v.y + v.z + v.w;
  float sq = v.x * v.x + v.y * v.y + v.z * v.z + v.w * v.w;
#pragma unroll
  for (int off = 32; off > 0; off >>= 1) {
    s += __shfl_down(s, off);
    sq += __shfl_down(sq, off);
  }
  __shared__ float red[8];
  const int w = t >> 6;
  if ((t & 63) == 0) { red[w] = s; red[4 + w] = sq; }
  __syncthreads();
  const float ts = red[0] + red[1] + red[2] + red[3];
  const float tq = red[4] + red[5] + red[6] + red[7];
  const float mean = ts * (1.0f / 1024.0f);
  float var = (tq - ts * mean) * (1.0f / 1023.0f);
  var = fmaxf(var, 0.0f);
  const float rden = 1.0f / (sqrtf(var) + 1e-5f);
  const float a = alpha_p[0], bb = beta_p[0];
  uint2 ov;
  ov.x = cvt_pk_bf16(a * (v.x - mean) * rden + bb, a * (v.y - mean) * rden + bb);
  ov.y = cvt_pk_bf16(a * (v.z - mean) * rden + bb, a * (v.w - mean) * rden + bb);
  reinterpret_cast<uint2*>(out + (size_t)row * 1024)[t] = ov;
}

// ---------- weight convert fp32 [K][N] -> bf16 transposed [N][K], optional scale ----------
__global__ __launch_bounds__(256) void wcvt_t(
    const float* __restrict__ w, u16* __restrict__ wt, int K, int N, float scale) {
  __shared__ float tile[32][33];
  const int n0 = blockIdx.x * 32, k0 = blockIdx.y * 32;
  const int tx = threadIdx.x, ty = threadIdx.y;
#pragma unroll
  for (int i = 0; i < 4; ++i)
    tile[ty + i * 8][tx] = w[(size_t)(k0 + ty + i * 8) * N + n0 + tx];
  __syncthreads();
#pragma unroll
  for (int i = 0; i < 4; ++i)
    wt[(size_t)(n0 + ty + i * 8) * K + k0 + tx] = f2bf(tile[tx][ty + i * 8] * scale);
}

// ---------- bias concat (bq pre-scaled) ----------
__global__ __launch_bounds__(256) void pack_bias(
    const float* __restrict__ a, const float* __restrict__ b,
    const float* __restrict__ c, float* __restrict__ o, float qscale) {
  const int i = blockIdx.x * 256 + threadIdx.x;
  o[i] = (i < 1024) ? a[i] * qscale : ((i < 2048) ? b[i - 1024] : c[i - 2048]);
}

// ---------- mask bias (log2 domain) + per-batch all-live flag ----------
__global__ __launch_bounds__(256) void mk_mbias(
    const int* __restrict__ mask, float* __restrict__ mb, int* __restrict__ flags) {
  const int b = blockIdx.x, t = threadIdx.x;
  __shared__ int bad;
  if (t == 0) bad = 0;
  __syncthreads();
  int loc = 0;
#pragma unroll
  for (int i = 0; i < 8; ++i) {
    const int idx = b * 2048 + t * 8 + i;
    const int mv = mask[idx];
    mb[idx] = mv ? 0.f : -1.4427e9f;
    loc |= (mv == 0);
  }
  if (loc) atomicOr(&bad, 1);
  __syncthreads();
  if (t == 0) flags[b] = !bad;
}

// ---------- GEMM (m97 structure + XCD swizzle) ----------
// EPI 0: bf16 out.  EPI 1: f32 out = acc+bias+res.  EPI 2: bf16 relu out.
// EPI 3: QKV — cols<2048 bf16 to Cout; cols>=2048 transposed to vt [B][1024][2048].
template <int EPI>
__global__ __launch_bounds__(256) void gemm_bt(
    const u16* __restrict__ A, const u16* __restrict__ Bt,
    const float* __restrict__ bias, const float* __restrict__ res,
    void* __restrict__ Cout, u16* __restrict__ vt, int M, int N, int K) {
  __shared__ u16 As[128 * 32];
  __shared__ u16 Bs[128 * 32];
  const int tid = threadIdx.x;
  const int l = tid & 63;
  const int w = tid >> 6;
  const int wr = w >> 1, wc = w & 1;
  // bijective XCD swizzle (all grids have nwg % 8 == 0)
  const int gx = gridDim.x;
  int id = blockIdx.y * gx + blockIdx.x;
  const int nwg = gx * gridDim.y;
  id = (id & 7) * (nwg >> 3) + (id >> 3);
  const int n0 = (id % gx) * 128;
  const int m0 = (id / gx) * 128;
  const int lr = l & 15, lk = (l >> 4) * 8;

  f32x4 acc[4][4];
#pragma unroll
  for (int i = 0; i < 4; ++i)
#pragma unroll
    for (int j = 0; j < 4; ++j) acc[i][j] = f32x4{0.f, 0.f, 0.f, 0.f};

  const int srow = tid >> 2;
  const int scol = (tid & 3) * 8;
  const u16* gA0 = A + (size_t)(m0 + srow) * K + scol;
  const u16* gA1 = A + (size_t)(m0 + 64 + srow) * K + scol;
  const u16* gB0 = Bt + (size_t)(n0 + srow) * K + scol;
  const u16* gB1 = Bt + (size_t)(n0 + 64 + srow) * K + scol;
  u16* lA0 = &As[tid * 8];
  u16* lA1 = &As[2048 + tid * 8];
  u16* lB0 = &Bs[tid * 8];
  u16* lB1 = &Bs[2048 + tid * 8];

  for (int k0 = 0; k0 < K; k0 += 32) {
    gld_lds16(gA0 + k0, lA0);
    gld_lds16(gA1 + k0, lA1);
    gld_lds16(gB0 + k0, lB0);
    gld_lds16(gB1 + k0, lB1);
    __syncthreads();
    bf16x8 a[4], b[4];
#pragma unroll
    for (int mf = 0; mf < 4; ++mf)
      a[mf] = *reinterpret_cast<const bf16x8*>(&As[(wr * 64 + mf * 16 + lr) * 32 + lk]);
#pragma unroll
    for (int nf = 0; nf < 4; ++nf)
      b[nf] = *reinterpret_cast<const bf16x8*>(&Bs[(wc * 64 + nf * 16 + lr) * 32 + lk]);
#pragma unroll
    for (int mf = 0; mf < 4; ++mf)
#pragma unroll
      for (int nf = 0; nf < 4; ++nf)
        acc[mf][nf] = __builtin_amdgcn_mfma_f32_16x16x32_bf16(a[mf], b[nf], acc[mf][nf], 0, 0, 0);
    __syncthreads();
  }

  if (EPI == 3 && n0 >= 2048) {
    // V block: transposed packed store into vt [B][1024][2048]
#pragma unroll
    for (int mf = 0; mf < 4; ++mf) {
#pragma unroll
      for (int nf = 0; nf < 4; ++nf) {
        const int col = n0 + wc * 64 + nf * 16 + lr;
        const float bv = bias[col];
        const int row0 = m0 + wr * 64 + mf * 16 + (l >> 4) * 4;
        const int bb = row0 >> 11, s0 = row0 & 2047;
        const int d = col - 2048;
        uint2 pv;
        pv.x = cvt_pk_bf16(acc[mf][nf][0] + bv, acc[mf][nf][1] + bv);
        pv.y = cvt_pk_bf16(acc[mf][nf][2] + bv, acc[mf][nf][3] + bv);
        *reinterpret_cast<uint2*>(vt + ((size_t)bb * 1024 + d) * 2048 + s0) = pv;
      }
    }
    return;
  }

#pragma unroll
  for (int mf = 0; mf < 4; ++mf) {
#pragma unroll
    for (int nf = 0; nf < 4; ++nf) {
      const int col = n0 + wc * 64 + nf * 16 + lr;
      const float bv = bias[col];
#pragma unroll
      for (int j = 0; j < 4; ++j) {
        const int row = m0 + wr * 64 + mf * 16 + (l >> 4) * 4 + j;
        const size_t idx = (size_t)row * N + col;
        const float vv = acc[mf][nf][j] + bv;
        if (EPI == 0 || EPI == 3)
          ((u16*)Cout)[idx] = f2bf(vv);
        else if (EPI == 1)
          ((float*)Cout)[idx] = vv + res[idx];
        else
          ((u16*)Cout)[idx] = f2bf(fmaxf(vv, 0.f));
      }
    }
  }
}

// ---------- flash attention, swapped QK^T, in-register softmax ----------
// qkv: [B*S][3072] bf16 (Q pre-scaled to exp2 domain at +0, K at +1024).
// vt: [B][1024][2048] bf16. mbias: [B][2048] f32 (log2 domain). flags: [B] all-live.
__global__ __launch_bounds__(256, 4) void attn_fwd4(
    const u16* __restrict__ qkv, const u16* __restrict__ vt,
    const float* __restrict__ mbias, const int* __restrict__ flags,
    u16* __restrict__ ctx) {
  __shared__ u16 Ks[2][64 * 64];
  __shared__ u16 Vs[2][64 * 64];
  const int tid = threadIdx.x;
  const int l = tid & 63;
  const int w = tid >> 6;
  const int b = blockIdx.y >> 4, h = blockIdx.y & 15;
  const int r0 = blockIdx.x * 128 + w * 32;
  const int lr = l & 15, lg = l >> 4;

  const u16* qb = qkv + (size_t)b * 2048 * 3072 + h * 64;
  const u16* kp = qb + 1024;
  const u16* vb = vt + ((size_t)b * 1024 + h * 64) * 2048;
  const float* mb = mbias + (size_t)b * 2048;
  const int allLive = flags[b];

  // Q as B-fragment: Q[q = r0+m*16+lr][dk = ks*32 + lg*8 + e]
  bf16x8 qf[2][2];
#pragma unroll
  for (int m = 0; m < 2; ++m)
#pragma unroll
    for (int ks = 0; ks < 2; ++ks)
      qf[m][ks] = *reinterpret_cast<const bf16x8*>(
          qb + (size_t)(r0 + m * 16 + lr) * 3072 + ks * 32 + lg * 8);

  float mrun[2] = {-1e30f, -1e30f};
  float lrun[2] = {0.f, 0.f};
  f32x4 o[2][4];
#pragma unroll
  for (int m = 0; m < 2; ++m)
#pragma unroll
    for (int d = 0; d < 4; ++d) o[m][d] = f32x4{0.f, 0.f, 0.f, 0.f};

  // staging: LDS linear dest, pre-swizzled global source (chunk ^= row&7)
  const u16* kS[2];
  const u16* vS[2];
#pragma unroll
  for (int i = 0; i < 2; ++i) {
    const int ci = tid + i * 256;
    const int row = ci >> 3, cc = ci & 7;
    const int sc = cc ^ (row & 7);
    kS[i] = kp + (size_t)row * 3072 + sc * 8;
    vS[i] = vb + (size_t)row * 2048 + sc * 8;
  }
#pragma unroll
  for (int i = 0; i < 2; ++i) {
    const int ci8 = (tid + i * 256) * 8;
    gld_lds16(kS[i], &Ks[0][ci8]);
    gld_lds16(vS[i], &Vs[0][ci8]);
  }
  asm volatile("s_waitcnt vmcnt(0)" ::: "memory");
  __syncthreads();

  union U8 { unsigned u[4]; bf16x8 v; };

  int cur = 0;
  for (int t = 0; t < 32; ++t) {
    const int kb0 = t * 64;
    if (t + 1 < 32) {
      const int nb = kb0 + 64;
#pragma unroll
      for (int i = 0; i < 2; ++i) {
        const int ci8 = (tid + i * 256) * 8;
        gld_lds16(kS[i] + (size_t)nb * 3072, &Ks[cur ^ 1][ci8]);
        gld_lds16(vS[i] + nb, &Vs[cur ^ 1][ci8]);
      }
    }

    // ---- QK^T swapped: st[m][cf] = P^T tile (exp2 domain; Q pre-scaled) ----
    f32x4 st[2][4];
    __builtin_amdgcn_s_setprio(1);
#pragma unroll
    for (int cf = 0; cf < 4; ++cf) {
      const int krow = cf * 16 + lr;
      const int ch0 = lg ^ (krow & 7);
      const int ch1 = (4 + lg) ^ (krow & 7);
      const bf16x8 kf0 = *reinterpret_cast<const bf16x8*>(&Ks[cur][krow * 64 + ch0 * 8]);
      const bf16x8 kf1 = *reinterpret_cast<const bf16x8*>(&Ks[cur][krow * 64 + ch1 * 8]);
#pragma unroll
      for (int m = 0; m < 2; ++m) {
        f32x4 acc = __builtin_amdgcn_mfma_f32_16x16x32_bf16(kf0, qf[m][0],
                                                            f32x4{0.f, 0.f, 0.f, 0.f}, 0, 0, 0);
        st[m][cf] = __builtin_amdgcn_mfma_f32_16x16x32_bf16(kf1, qf[m][1], acc, 0, 0, 0);
      }
    }
    __builtin_amdgcn_s_setprio(0);

    // ---- additive mask only when some kv are masked (uniform branch) ----
    if (!allLive) {
#pragma unroll
      for (int cf = 0; cf < 4; ++cf) {
        const float4 m4 = *reinterpret_cast<const float4*>(mb + kb0 + cf * 16 + lg * 4);
#pragma unroll
        for (int m = 0; m < 2; ++m) {
          st[m][cf][0] += m4.x;
          st[m][cf][1] += m4.y;
          st[m][cf][2] += m4.z;
          st[m][cf][3] += m4.w;
        }
      }
    }

    // ---- per-m: in-register softmax + P->bf16 exchange ----
    bf16x8 paA[2], paB[2];
#pragma unroll
    for (int m = 0; m < 2; ++m) {
      float pm = fmaxf(fmaxf(st[m][0][0], st[m][0][1]), fmaxf(st[m][0][2], st[m][0][3]));
#pragma unroll
      for (int cf = 1; cf < 4; ++cf)
        pm = fmaxf(pm, fmaxf(fmaxf(st[m][cf][0], st[m][cf][1]),
                             fmaxf(st[m][cf][2], st[m][cf][3])));
      pm = fmaxf(pm, __shfl_xor(pm, 16));
      pm = fmaxf(pm, __shfl_xor(pm, 32));
      if (__any(pm > mrun[m] + 8.f)) {          // defer-max (T13)
        const float mn = fmaxf(mrun[m], pm);
        const float corr = exp2f(mrun[m] - mn);
        mrun[m] = mn;
        lrun[m] *= corr;
#pragma unroll
        for (int d = 0; d < 4; ++d)
#pragma unroll
          for (int j = 0; j < 4; ++j) o[m][d][j] *= corr;
      }
      float rs = 0.f;
#pragma unroll
      for (int cf = 0; cf < 4; ++cf)
#pragma unroll
        for (int j = 0; j < 4; ++j) {
          const float p = exp2f(st[m][cf][j] - mrun[m]);
          st[m][cf][j] = p;
          rs += p;
        }
      rs += __shfl_xor(rs, 16);
      rs += __shfl_xor(rs, 32);
      lrun[m] += rs;

      // pack to bf16 pairs: pk[cf][wp] = kv (16cf+4lg+2wp, +1)
      unsigned pk[4][2];
#pragma unroll
      for (int cf = 0; cf < 4; ++cf)
#pragma unroll
        for (int wp = 0; wp < 2; ++wp)
          pk[cf][wp] = cvt_pk_bf16(st[m][cf][2 * wp], st[m][cf][2 * wp + 1]);

      // exchange: dest lane lg needs kv = 32ks+8lg+2w from lane (2lg+(w>>1))&3,
      // word pk[2ks + (lg>>1)][w&1]
      U8 a0, a1;
#pragma unroll
      for (int c = 0; c < 2; ++c) {
        const int src = lr + 16 * ((2 * lg + c) & 3);
#pragma unroll
        for (int wp = 0; wp < 2; ++wp) {
          const int v00 = __shfl((int)pk[0][wp], src);
          const int v01 = __shfl((int)pk[1][wp], src);
          const int v10 = __shfl((int)pk[2][wp], src);
          const int v11 = __shfl((int)pk[3][wp], src);
          a0.u[2 * c + wp] = (unsigned)((lg < 2) ? v00 : v01);
          a1.u[2 * c + wp] = (unsigned)((lg < 2) ? v10 : v11);
        }
      }
      paA[m] = a0.v;
      paB[m] = a1.v;
    }

    // ---- PV: O^T += V^T_tile · P^T ----
    __builtin_amdgcn_s_setprio(1);
#pragma unroll
    for (int df = 0; df < 4; ++df) {
      const int vrow = df * 16 + lr;
      const int ch0 = lg ^ (vrow & 7);
      const int ch1 = (4 + lg) ^ (vrow & 7);
      const bf16x8 vf0 = *reinterpret_cast<const bf16x8*>(&Vs[cur][vrow * 64 + ch0 * 8]);
      const bf16x8 vf1 = *reinterpret_cast<const bf16x8*>(&Vs[cur][vrow * 64 + ch1 * 8]);
#pragma unroll
      for (int m = 0; m < 2; ++m) {
        o[m][df] = __builtin_amdgcn_mfma_f32_16x16x32_bf16(vf0, paA[m], o[m][df], 0, 0, 0);
        o[m][df] = __builtin_amdgcn_mfma_f32_16x16x32_bf16(vf1, paB[m], o[m][df], 0, 0, 0);
      }
    }
    __builtin_amdgcn_s_setprio(0);

    asm volatile("s_waitcnt vmcnt(0)" ::: "memory");
    __syncthreads();
    cur ^= 1;
  }

  // ---- epilogue: O^T[d][q], packed 8B stores ----
#pragma unroll
  for (int m = 0; m < 2; ++m) {
    const float rdiv = 1.f / lrun[m];
    const size_t rowbase = ((size_t)b * 2048 + r0 + m * 16 + lr) * 1024 + h * 64;
#pragma unroll
    for (int df = 0; df < 4; ++df) {
      uint2 s4;
      s4.x = cvt_pk_bf16(o[m][df][0] * rdiv, o[m][df][1] * rdiv);
      s4.y = cvt_pk_bf16(o[m][df][2] * rdiv, o[m][df][3] * rdiv);
      *reinterpret_cast<uint2*>(ctx + rowbase + df * 16 + lg * 4) = s4;
    }
  }
}

// ---------- launch ----------
extern "C" void kernel_launch(void* const* d_in, const int* in_sizes, int n_in,
                              void* d_out, int out_size, void* d_ws, size_t ws_size,
                              hipStream_t stream) {
  const float* x = (const float*)d_in[0];
  const int* mask = (const int*)d_in[1];
  const float* wq = (const float*)d_in[2];
  const float* bq = (const float*)d_in[3];
  const float* wk = (const float*)d_in[4];
  const float* bk = (const float*)d_in[5];
  const float* wv = (const float*)d_in[6];
  const float* bv = (const float*)d_in[7];
  const float* wo = (const float*)d_in[8];
  const float* bo = (const float*)d_in[9];
  const float* w1 = (const float*)d_in[10];
  const float* b1 = (const float*)d_in[11];
  const float* w2 = (const float*)d_in[12];
  const float* b2 = (const float*)d_in[13];
  const float* ln1a = (const float*)d_in[14];
  const float* ln1b = (const float*)d_in[15];
  const float* ln2a = (const float*)d_in[16];
  const float* ln2b = (const float*)d_in[17];

  const float SCL2 = 0.125f * 1.4426950408889634f;  // 1/sqrt(dk) * log2(e)

  char* ws = (char*)d_ws;
  const size_t MB = 1024ull * 1024ull;
  u16* WTQKV = (u16*)(ws + 0 * MB);    // [3072][1024] bf16, 6MB
  u16* WTO = (u16*)(ws + 6 * MB);      // 2MB
  u16* W1T = (u16*)(ws + 8 * MB);      // [4096][1024], 8MB
  u16* W2T = (u16*)(ws + 16 * MB);     // [1024][4096], 8MB
  float* BQKV = (float*)(ws + 24 * MB);              // 12KB
  float* MBIAS = (float*)(ws + 24 * MB + 65536);     // 32KB
  int* FLAGS = (int*)(ws + 24 * MB + 131072);        // 16B
  u16* QKV = (u16*)(ws + 25 * MB);     // [8192][3072] bf16 (Q,K cols used), 48MB (25-73)
  u16* VT = (u16*)(ws + 73 * MB);      // [4][1024][2048] bf16, 16MB (73-89)
  u16* XN = (u16*)(ws + 89 * MB);      // 16MB (89-105); dead after QKV gemm
  u16* CTX = (u16*)(ws + 105 * MB);    // 16MB (105-121)
  float* X2 = (float*)(ws + 25 * MB);  // 32MB (25-57), overwrites QKV after attn
  u16* XN2 = (u16*)(ws + 57 * MB);     // 16MB (57-73)
  u16* H1 = (u16*)(ws + 73 * MB);      // [8192][4096] bf16, 64MB (73-137)

  dim3 bt(32, 8);
  wcvt_t<<<dim3(32, 32), bt, 0, stream>>>(wq, WTQKV, 1024, 1024, SCL2);
  wcvt_t<<<dim3(32, 32), bt, 0, stream>>>(wk, WTQKV + 1024 * 1024, 1024, 1024, 1.f);
  wcvt_t<<<dim3(32, 32), bt, 0, stream>>>(wv, WTQKV + 2048 * 1024, 1024, 1024, 1.f);
  wcvt_t<<<dim3(32, 32), bt, 0, stream>>>(wo, WTO, 1024, 1024, 1.f);
  wcvt_t<<<dim3(128, 32), bt, 0, stream>>>(w1, W1T, 1024, 4096, 1.f);
  wcvt_t<<<dim3(32, 128), bt, 0, stream>>>(w2, W2T, 4096, 1024, 1.f);
  pack_bias<<<dim3(12), 256, 0, stream>>>(bq, bk, bv, BQKV, SCL2);
  mk_mbias<<<dim3(4), 256, 0, stream>>>(mask, MBIAS, FLAGS);

  ln_kernel<<<8192, 256, 0, stream>>>(x, XN, ln1a, ln1b);
  // fused QKV projection; V written transposed to VT
  gemm_bt<3><<<dim3(24, 64), 256, 0, stream>>>(XN, WTQKV, BQKV, nullptr, QKV, VT, 8192, 3072, 1024);
  attn_fwd4<<<dim3(16, 64), 256, 0, stream>>>(QKV, VT, MBIAS, FLAGS, CTX);
  gemm_bt<1><<<dim3(8, 64), 256, 0, stream>>>(CTX, WTO, bo, x, X2, nullptr, 8192, 1024, 1024);
  ln_kernel<<<8192, 256, 0, stream>>>(X2, XN2, ln2a, ln2b);
  gemm_bt<2><<<dim3(32, 64), 256, 0, stream>>>(XN2, W1T, b1, nullptr, H1, nullptr, 8192, 4096, 1024);
  gemm_bt<1><<<dim3(8, 64), 256, 0, stream>>>(H1, W2T, b2, X2, (float*)d_out, nullptr, 8192, 1024, 4096);
}